// Round 5
// baseline (781.712 us; speedup 1.0000x reference)
//
#include <hip/hip_runtime.h>
#include <hip/hip_bf16.h>
#include <stdint.h>

#define D_DIM 1024
#define E_NUM 8
#define H_DIM 4096

typedef __attribute__((ext_vector_type(8))) short short8;
typedef __attribute__((ext_vector_type(4))) short short4v;
typedef __attribute__((ext_vector_type(4))) unsigned short ushort4v;
typedef __attribute__((ext_vector_type(4))) float f32x4;

#define GLOBAL_AS __attribute__((address_space(1)))
#define LDS_AS __attribute__((address_space(3)))

__device__ __forceinline__ void async_load16(const void* g, void* l) {
    __builtin_amdgcn_global_load_lds((GLOBAL_AS void*)g, (LDS_AS void*)l, 16, 0, 0);
}

// tanh-form gelu, branchless. |err| <= ~3e-4.
__device__ __forceinline__ float gelu_fast(float x) {
    float x3 = x * x * x;
    float z = 0.7978845608028654f * x + 0.0356774081363001f * x3;
    float u = __expf(-2.0f * fabsf(z));
    float t = __fdividef(1.0f - u, 1.0f + u);
    t = copysignf(t, z);
    return 0.5f * x * (1.0f + t);
}

__device__ __forceinline__ float b2f(short s) {
    union { float f; unsigned u; } x; x.u = ((unsigned)(unsigned short)s) << 16; return x.f;
}

__device__ __forceinline__ unsigned short f2b(float f) {
    union { __hip_bfloat16 h; unsigned short s; } u;
    u.h = __float2bfloat16(f);
    return u.s;
}

// ---------------- router: logits (fp64), softmax, top-2; float2-vectorized x; fused x->bf16 ----------------
__global__ __launch_bounds__(256) void router_kernel(
    const float* __restrict__ x, const float* __restrict__ Wg,
    __hip_bfloat16* __restrict__ xb, int* __restrict__ epick,
    float* __restrict__ ewgt, int T) {
    int gwave = (int)((blockIdx.x * 256 + threadIdx.x) >> 6);
    int lane = threadIdx.x & 63;
    if (gwave >= T) return;
    const float* xr = x + (size_t)gwave * D_DIM;
    unsigned short* xbr = (unsigned short*)xb + (size_t)gwave * D_DIM;
    double acc[E_NUM];
#pragma unroll
    for (int e = 0; e < E_NUM; ++e) acc[e] = 0.0;
#pragma unroll
    for (int i = 0; i < D_DIM / 128; ++i) {
        int d = i * 128 + lane * 2;
        float2 xv = *(const float2*)(xr + d);
        unsigned pk = (unsigned)f2b(xv.x) | ((unsigned)f2b(xv.y) << 16);
        *(unsigned*)(xbr + d) = pk;
        const float4* wg0 = (const float4*)(Wg + (size_t)d * E_NUM);
        const float4* wg1 = (const float4*)(Wg + (size_t)(d + 1) * E_NUM);
        float4 wa = wg0[0], wb = wg0[1], wc = wg1[0], wd = wg1[1];
        double x0 = (double)xv.x, x1 = (double)xv.y;
        acc[0] += x0 * (double)wa.x + x1 * (double)wc.x;
        acc[1] += x0 * (double)wa.y + x1 * (double)wc.y;
        acc[2] += x0 * (double)wa.z + x1 * (double)wc.z;
        acc[3] += x0 * (double)wa.w + x1 * (double)wc.w;
        acc[4] += x0 * (double)wb.x + x1 * (double)wd.x;
        acc[5] += x0 * (double)wb.y + x1 * (double)wd.y;
        acc[6] += x0 * (double)wb.z + x1 * (double)wd.z;
        acc[7] += x0 * (double)wb.w + x1 * (double)wd.w;
    }
#pragma unroll
    for (int s = 32; s > 0; s >>= 1) {
#pragma unroll
        for (int e = 0; e < E_NUM; ++e) acc[e] += __shfl_xor(acc[e], s);
    }
    double mx = acc[0];
#pragma unroll
    for (int e = 1; e < E_NUM; ++e) mx = fmax(mx, acc[e]);
    double p[E_NUM]; double sum = 0.0;
#pragma unroll
    for (int e = 0; e < E_NUM; ++e) { p[e] = exp(acc[e] - mx); sum += p[e]; }
    int i0 = 0;
#pragma unroll
    for (int e = 1; e < E_NUM; ++e) if (p[e] > p[i0]) i0 = e;
    int i1 = (i0 == 0) ? 1 : 0;
#pragma unroll
    for (int e = 0; e < E_NUM; ++e) if (e != i0 && p[e] > p[i1]) i1 = e;
    if (lane == 0) {
        epick[gwave] = i0 | (i1 << 8);
        ewgt[2 * gwave]     = (float)(p[i0] / sum);
        ewgt[2 * gwave + 1] = (float)(p[i1] / sum);
    }
}

// ---------------- bucket: block-aggregated scatter; 8 global atomics per block ----------------
__global__ __launch_bounds__(256) void bucket_kernel(
    const int* __restrict__ epick, int* __restrict__ cnt,
    int* __restrict__ tok, int* __restrict__ eidx, int T) {
    __shared__ int lcnt[E_NUM];
    __shared__ int gbase[E_NUM];
    int b = blockIdx.x, tid = threadIdx.x;
    if (tid < E_NUM) lcnt[tid] = 0;
    __syncthreads();
    int t = b * 128 + (tid >> 1);
    int j = tid & 1;
    int e = (epick[t] >> (j * 8)) & 0xff;
    int li = atomicAdd(&lcnt[e], 1);
    __syncthreads();
    if (tid < E_NUM) gbase[tid] = atomicAdd(&cnt[tid], lcnt[tid]);
    __syncthreads();
    int slot = gbase[e] + li;
    tok[e * T + slot] = t;
    eidx[2 * t + j] = (e << 16) | slot;
}

__global__ void prefix_kernel(const int* __restrict__ cnt, int* __restrict__ base) {
    if (threadIdx.x == 0) {
        int a = 0;
#pragma unroll
        for (int e = 0; e < E_NUM; ++e) { base[e] = a; a += cnt[e]; }
    }
}

// ---------------- unified W1/W2 transpose, 64x64 tiles, packed stores ----------------
// W1: [E][D][H] f32 -> w1t [E][H][D] bf16 (no perm).
// W2: [E][H][D] f32 -> w2t [E][D][H] bf16 with K(=H) perm pi(j)=(j&3)*16+(j>>2) per 64-block.
__global__ __launch_bounds__(256) void transpose_both_kernel(
    const float* __restrict__ W1, const float* __restrict__ W2,
    __hip_bfloat16* __restrict__ w1t, __hip_bfloat16* __restrict__ w2t) {
    __shared__ float tile[64][65];
    int e = blockIdx.z;
    int id = blockIdx.x;
    const float* src; unsigned short* dst; int R, C, r0, c0, perm;
    if (id < 1024) {  // W1: R=D rows, C=H cols
        R = D_DIM; C = H_DIM;
        r0 = (id >> 6) * 64; c0 = (id & 63) * 64;
        src = W1 + (size_t)e * D_DIM * H_DIM;
        dst = (unsigned short*)(w1t + (size_t)e * H_DIM * D_DIM);
        perm = 0;
    } else {          // W2: R=H rows, C=D cols
        id -= 1024;
        R = H_DIM; C = D_DIM;
        r0 = (id >> 4) * 64; c0 = (id & 15) * 64;
        src = W2 + (size_t)e * H_DIM * D_DIM;
        dst = (unsigned short*)(w2t + (size_t)e * D_DIM * H_DIM);
        perm = 1;
    }
    int tx = threadIdx.x, ty = threadIdx.y;  // 32 x 8
#pragma unroll
    for (int i = 0; i < 8; ++i) {
        int j = ty + i * 8;
        int sr = perm ? ((j & 3) * 16 + (j >> 2)) : j;
        float2 v = *(const float2*)(src + (size_t)(r0 + sr) * C + c0 + 2 * tx);
        tile[j][2 * tx] = v.x; tile[j][2 * tx + 1] = v.y;
    }
    __syncthreads();
#pragma unroll
    for (int i = 0; i < 8; ++i) {
        int cc = ty + i * 8;
        unsigned pk = (unsigned)f2b(tile[2 * tx][cc]) | ((unsigned)f2b(tile[2 * tx + 1][cc]) << 16);
        *(unsigned*)(dst + (size_t)(c0 + cc) * R + r0 + 2 * tx) = pk;
    }
}

// ====================== GEMMs: proven round-0 128x128 2-barrier structure ======================
// Optimization ledger (harness-measured):
//  - 256x256 counted-vmcnt, coarse (r1): 282us, MfmaUtil 22 — REGRESSED (m196 pattern)
//  - 256x256 fine-phase m201-port (r3): 242us, MfmaUtil 25.6 — REGRESSED
//  - T1 XCD chunked swizzle (r4): FETCH 173->250MB, dur +3% — REGRESSED (early-exit
//    blocks + gather break static locality analysis; default order wins)
//  -> This 128x128 / BK=32 / 4-wave / 2-barrier structure at ~3 blocks/CU is the
//     measured optimum for gemm1 (210us, 652 TF). Remaining gap to m97's 874 is
//     K=1024 amortization (per-block epilogue ~1300cy vs 32 K-iters) — inherent.
// LDS K-chunk swizzle (BK=32, 64 B rows = 4 chunks): row r chunk k stored at
// chunk r*4 + (k ^ ((r>>1)&3)). Writer (async, dest = base+lane*16): lane
// sources global chunk (lane&3)^((lane>>3)&3) of row (lane>>2). Reader: chunk
// q of row ra at byte ra*64 + ((q ^ ((ra>>1)&3))<<4). Conflict-free (measured
// SQ_LDS_BANK_CONFLICT = 0). Keep BK=32 (BK=64 regressed: occupancy 41->21).

// ---------------- GEMM1: h[slot, perm(col)] = gelu(x[tok] @ W1[e] + b1[e]), BK=32 ----------------
__global__ __launch_bounds__(256) void gemm1_kernel(
    const __hip_bfloat16* __restrict__ xb,   // [T][D]
    const __hip_bfloat16* __restrict__ w1t,  // [E][H][D] (B^T)
    const float* __restrict__ b1,            // [E][H]
    const int* __restrict__ cnt, const int* __restrict__ base,
    const int* __restrict__ tok,
    __hip_bfloat16* __restrict__ hbuf,       // [2T][H] (N-permuted)
    int T) {
    int e = blockIdx.z;
    int M = cnt[e];
    int m0 = blockIdx.y * 128;
    if (m0 >= M) return;
    int n0 = blockIdx.x * 128;
    const __hip_bfloat16* Bp = w1t + (size_t)e * H_DIM * D_DIM;

    __shared__ __align__(16) short sA[128 * 32];
    __shared__ __align__(16) short sB[128 * 32];
    __shared__ float sBias[128];
    char* sAc = (char*)sA; char* sBc = (char*)sB;

    int tid = threadIdx.x;
    int w = tid >> 6, lane = tid & 63;
    int wm = w >> 1, wn = w & 1;
    int q = lane >> 4, l4 = lane & 15;

    if (tid < 128) sBias[tid] = b1[e * H_DIM + n0 + tid];

    int kswz = ((lane & 3) ^ ((lane >> 3) & 3)) << 3;  // swizzled element offset
    int r0 = w * 32 + (lane >> 2);
    int r1 = r0 + 16;
    int tA0 = tok[e * T + min(m0 + r0, M - 1)];
    int tA1 = tok[e * T + min(m0 + r1, M - 1)];
    const __hip_bfloat16* gA0 = xb + (size_t)tA0 * D_DIM + kswz;
    const __hip_bfloat16* gA1 = xb + (size_t)tA1 * D_DIM + kswz;
    const __hip_bfloat16* gB0 = Bp + (size_t)(n0 + r0) * D_DIM + kswz;
    const __hip_bfloat16* gB1 = Bp + (size_t)(n0 + r1) * D_DIM + kswz;
    char* lA0 = sAc + w * 2048 + lane * 16;
    char* lB0 = sBc + w * 2048 + lane * 16;
    char* lA1 = sAc + w * 2048 + 1024;  // wave's second segment base
    char* lB1 = sBc + w * 2048 + 1024;

    f32x4 acc[4][4];
#pragma unroll
    for (int a = 0; a < 4; ++a)
#pragma unroll
        for (int b = 0; b < 4; ++b) acc[a][b] = (f32x4){0.f, 0.f, 0.f, 0.f};

    for (int kk = 0; kk < D_DIM; kk += 32) {
        async_load16(gA0 + kk, lA0);
        async_load16(gA1 + kk, lA1);
        async_load16(gB0 + kk, lB0);
        async_load16(gB1 + kk, lB1);
        __syncthreads();
        short8 aF[4], bF[4];
#pragma unroll
        for (int t = 0; t < 4; ++t) {
            int ra = wm * 64 + t * 16 + l4;
            aF[t] = *(const short8*)(sAc + ra * 64 + ((q ^ ((ra >> 1) & 3)) << 4));
            int rb = wn * 64 + t * 16 + l4;
            bF[t] = *(const short8*)(sBc + rb * 64 + ((q ^ ((rb >> 1) & 3)) << 4));
        }
#pragma unroll
        for (int tm = 0; tm < 4; ++tm)
#pragma unroll
            for (int tn = 0; tn < 4; ++tn)
                acc[tm][tn] = __builtin_amdgcn_mfma_f32_16x16x32_bf16(aF[tm], bF[tn], acc[tm][tn], 0, 0, 0);
        __syncthreads();
    }

    int sb = base[e];
    unsigned short* hs = (unsigned short*)hbuf;
#pragma unroll
    for (int tm = 0; tm < 4; ++tm) {
        int rbase = wm * 64 + tm * 16 + q * 4;
#pragma unroll
        for (int i = 0; i < 4; ++i) {
            int row = m0 + rbase + i;
            if (row < M) {
                size_t hrow = (size_t)(sb + row) * H_DIM;
                ushort4v pk;
#pragma unroll
                for (int tn = 0; tn < 4; ++tn) {
                    float v = acc[tm][tn][i] + sBias[wn * 64 + tn * 16 + l4];
                    pk[tn] = f2b(gelu_fast(v));
                }
                *(ushort4v*)(hs + hrow + n0 + wn * 64 + l4 * 4) = pk;
            }
        }
    }
}

// ---------------- GEMM2 (full K=4096, BK=32): ybuf[slot, perm(col)] = h @ W2[e] ----------------
// r5: split-K removed. Supply 1024 working blocks = 4/CU, matching the observed
// ~3.2 sustained blocks/CU; per-block overhead amortizes over 128 K-iters
// (vs 64), and partial-write traffic (33.5MB write + 33.5MB combine read) is
// deleted. f32 accumulation over full K also tightens numerics vs summing two
// bf16-rounded partials.
__global__ __launch_bounds__(256) void gemm2_kernel(
    const __hip_bfloat16* __restrict__ hbuf, // [2T][H] (K-permuted, matches w2t)
    const __hip_bfloat16* __restrict__ w2t,  // [E][D][H] (B^T, K-permuted)
    const int* __restrict__ cnt, const int* __restrict__ base,
    __hip_bfloat16* __restrict__ ybuf,       // [2T][D] (N-permuted)
    int T) {
    int e = blockIdx.z;
    int M = cnt[e];
    int m0 = blockIdx.y * 128;
    if (m0 >= M) return;
    int n0 = blockIdx.x * 128;
    int sb = base[e];
    const __hip_bfloat16* Bp = w2t + (size_t)e * D_DIM * H_DIM;

    __shared__ __align__(16) short sA[128 * 32];
    __shared__ __align__(16) short sB[128 * 32];
    char* sAc = (char*)sA; char* sBc = (char*)sB;

    int tid = threadIdx.x;
    int w = tid >> 6, lane = tid & 63;
    int wm = w >> 1, wn = w & 1;
    int q = lane >> 4, l4 = lane & 15;

    int kswz = ((lane & 3) ^ ((lane >> 3) & 3)) << 3;
    int r0 = w * 32 + (lane >> 2);
    int r1 = r0 + 16;
    const __hip_bfloat16* gA0 = hbuf + (size_t)(sb + min(m0 + r0, M - 1)) * H_DIM + kswz;
    const __hip_bfloat16* gA1 = hbuf + (size_t)(sb + min(m0 + r1, M - 1)) * H_DIM + kswz;
    const __hip_bfloat16* gB0 = Bp + (size_t)(n0 + r0) * H_DIM + kswz;
    const __hip_bfloat16* gB1 = Bp + (size_t)(n0 + r1) * H_DIM + kswz;
    char* lA0 = sAc + w * 2048 + lane * 16;
    char* lB0 = sBc + w * 2048 + lane * 16;
    char* lA1 = sAc + w * 2048 + 1024;
    char* lB1 = sBc + w * 2048 + 1024;

    f32x4 acc[4][4];
#pragma unroll
    for (int a = 0; a < 4; ++a)
#pragma unroll
        for (int b = 0; b < 4; ++b) acc[a][b] = (f32x4){0.f, 0.f, 0.f, 0.f};

    for (int kk = 0; kk < H_DIM; kk += 32) {
        async_load16(gA0 + kk, lA0);
        async_load16(gA1 + kk, lA1);
        async_load16(gB0 + kk, lB0);
        async_load16(gB1 + kk, lB1);
        __syncthreads();
        short8 aF[4], bF[4];
#pragma unroll
        for (int t = 0; t < 4; ++t) {
            int ra = wm * 64 + t * 16 + l4;
            aF[t] = *(const short8*)(sAc + ra * 64 + ((q ^ ((ra >> 1) & 3)) << 4));
            int rb = wn * 64 + t * 16 + l4;
            bF[t] = *(const short8*)(sBc + rb * 64 + ((q ^ ((rb >> 1) & 3)) << 4));
        }
#pragma unroll
        for (int tm = 0; tm < 4; ++tm)
#pragma unroll
            for (int tn = 0; tn < 4; ++tn)
                acc[tm][tn] = __builtin_amdgcn_mfma_f32_16x16x32_bf16(aF[tm], bF[tn], acc[tm][tn], 0, 0, 0);
        __syncthreads();
    }

    unsigned short* ys = (unsigned short*)ybuf;
#pragma unroll
    for (int tm = 0; tm < 4; ++tm) {
        int rbase = wm * 64 + tm * 16 + q * 4;
#pragma unroll
        for (int i = 0; i < 4; ++i) {
            int row = m0 + rbase + i;
            if (row < M) {
                size_t yrow = (size_t)(sb + row) * D_DIM;
                ushort4v pk;
#pragma unroll
                for (int tn = 0; tn < 4; ++tn) pk[tn] = f2b(acc[tm][tn][i]);
                *(ushort4v*)(ys + yrow + n0 + wn * 64 + l4 * 4) = pk;
            }
        }
    }
}

// ---------------- combine: out[t, pi(c)] = sum_j w_j * (y_j + b2[e_j]) ----------------
__global__ __launch_bounds__(256) void combine_kernel(
    const __hip_bfloat16* __restrict__ yb, const float* __restrict__ b2,
    const int* __restrict__ base, const int* __restrict__ eidx,
    const float* __restrict__ ewgt, float* __restrict__ out, int T) {
    int t = blockIdx.x, tid = threadIdx.x;
    int v0 = eidx[2 * t], v1 = eidx[2 * t + 1];
    float w0 = ewgt[2 * t], w1 = ewgt[2 * t + 1];
    int e0 = v0 >> 16, e1 = v1 >> 16;
    size_t g0 = (size_t)base[e0] + (v0 & 0xffff);
    size_t g1 = (size_t)base[e1] + (v1 & 0xffff);
    int c = tid * 4;               // stored (permuted) col
    int blk = c >> 6;
    int tt = (c >> 2) & 15;
    const short* ys = (const short*)yb;
    short4v a0 = *(const short4v*)(ys + g0 * D_DIM + c);
    short4v c0 = *(const short4v*)(ys + g1 * D_DIM + c);
    float s0[4] = { b2f(a0.x), b2f(a0.y), b2f(a0.z), b2f(a0.w) };
    float s1[4] = { b2f(c0.x), b2f(c0.y), b2f(c0.z), b2f(c0.w) };
    float* orow = out + (size_t)t * D_DIM;
#pragma unroll
    for (int s = 0; s < 4; ++s) {
        int oc = blk * 64 + s * 16 + tt;   // original col
        float o = w0 * (s0[s] + b2[(size_t)e0 * D_DIM + oc]) +
                  w1 * (s1[s] + b2[(size_t)e1 * D_DIM + oc]);
        orow[oc] = o;
    }
}

extern "C" void kernel_launch(void* const* d_in, const int* in_sizes, int n_in,
                              void* d_out, int out_size, void* d_ws, size_t ws_size,
                              hipStream_t stream) {
    const float* x  = (const float*)d_in[0];
    const float* Wg = (const float*)d_in[1];
    const float* W1 = (const float*)d_in[2];
    const float* b1 = (const float*)d_in[3];
    const float* W2 = (const float*)d_in[4];
    const float* b2 = (const float*)d_in[5];
    int T = in_sizes[0] / D_DIM;  // 8192

    char* p = (char*)d_ws;
    int* cnt   = (int*)p;
    int* base  = (int*)(p + 256);
    int* tok   = (int*)(p + 512);
    int* eidx  = (int*)(p + 512 + 4ll * E_NUM * T);
    float* ewgt = (float*)(p + 512 + 4ll * E_NUM * T + 8ll * T);
    int* epick = (int*)(p + 512 + 4ll * E_NUM * T + 16ll * T);
    char* pb = p + 512 + 4ll * E_NUM * T + 20ll * T;
    __hip_bfloat16* xb  = (__hip_bfloat16*)pb;
    __hip_bfloat16* w1t = xb + (size_t)T * D_DIM;
    __hip_bfloat16* w2t = w1t + (size_t)E_NUM * H_DIM * D_DIM;
    __hip_bfloat16* hb  = w2t + (size_t)E_NUM * H_DIM * D_DIM;
    // ybuf [2T][D] bf16 (33.5 MB) aliases xb+w1t (dead by gemm2 time).
    __hip_bfloat16* yb  = xb;

    hipMemsetAsync(cnt, 0, 256, stream);

    router_kernel<<<dim3((T + 3) / 4), 256, 0, stream>>>(x, Wg, xb, epick, ewgt, T);
    bucket_kernel<<<dim3(T / 128), 256, 0, stream>>>(epick, cnt, tok, eidx, T);
    prefix_kernel<<<1, 64, 0, stream>>>(cnt, base);
    transpose_both_kernel<<<dim3(2048, 1, E_NUM), dim3(32, 8), 0, stream>>>(W1, W2, w1t, w2t);
    gemm1_kernel<<<dim3(H_DIM / 128, T / 128, E_NUM), 256, 0, stream>>>(xb, w1t, b1, cnt, base, tok, hb, T);
    gemm2_kernel<<<dim3(D_DIM / 128, T / 128, E_NUM), 256, 0, stream>>>(hb, w2t, cnt, base, yb, T);
    combine_kernel<<<T, 256, 0, stream>>>(yb, b2, base, eidx, ewgt, (float*)d_out, T);
}

// Round 6
// 758.611 us; speedup vs baseline: 1.0305x; 1.0305x over previous
//
#include <hip/hip_runtime.h>
#include <hip/hip_bf16.h>
#include <stdint.h>

#define D_DIM 1024
#define E_NUM 8
#define H_DIM 4096

typedef __attribute__((ext_vector_type(8))) short short8;
typedef __attribute__((ext_vector_type(4))) short short4v;
typedef __attribute__((ext_vector_type(4))) unsigned short ushort4v;
typedef __attribute__((ext_vector_type(4))) float f32x4;

#define GLOBAL_AS __attribute__((address_space(1)))
#define LDS_AS __attribute__((address_space(3)))

__device__ __forceinline__ void async_load16(const void* g, void* l) {
    __builtin_amdgcn_global_load_lds((GLOBAL_AS void*)g, (LDS_AS void*)l, 16, 0, 0);
}

// tanh-form gelu, branchless. |err| <= ~3e-4.
__device__ __forceinline__ float gelu_fast(float x) {
    float x3 = x * x * x;
    float z = 0.7978845608028654f * x + 0.0356774081363001f * x3;
    float u = __expf(-2.0f * fabsf(z));
    float t = __fdividef(1.0f - u, 1.0f + u);
    t = copysignf(t, z);
    return 0.5f * x * (1.0f + t);
}

__device__ __forceinline__ float b2f(short s) {
    union { float f; unsigned u; } x; x.u = ((unsigned)(unsigned short)s) << 16; return x.f;
}

__device__ __forceinline__ unsigned short f2b(float f) {
    union { __hip_bfloat16 h; unsigned short s; } u;
    u.h = __float2bfloat16(f);
    return u.s;
}

// ---------------- router: logits (fp64), softmax, top-2; float2-vectorized x; fused x->bf16 ----------------
__global__ __launch_bounds__(256) void router_kernel(
    const float* __restrict__ x, const float* __restrict__ Wg,
    __hip_bfloat16* __restrict__ xb, int* __restrict__ epick,
    float* __restrict__ ewgt, int T) {
    int gwave = (int)((blockIdx.x * 256 + threadIdx.x) >> 6);
    int lane = threadIdx.x & 63;
    if (gwave >= T) return;
    const float* xr = x + (size_t)gwave * D_DIM;
    unsigned short* xbr = (unsigned short*)xb + (size_t)gwave * D_DIM;
    double acc[E_NUM];
#pragma unroll
    for (int e = 0; e < E_NUM; ++e) acc[e] = 0.0;
#pragma unroll
    for (int i = 0; i < D_DIM / 128; ++i) {
        int d = i * 128 + lane * 2;
        float2 xv = *(const float2*)(xr + d);
        unsigned pk = (unsigned)f2b(xv.x) | ((unsigned)f2b(xv.y) << 16);
        *(unsigned*)(xbr + d) = pk;
        const float4* wg0 = (const float4*)(Wg + (size_t)d * E_NUM);
        const float4* wg1 = (const float4*)(Wg + (size_t)(d + 1) * E_NUM);
        float4 wa = wg0[0], wb = wg0[1], wc = wg1[0], wd = wg1[1];
        double x0 = (double)xv.x, x1 = (double)xv.y;
        acc[0] += x0 * (double)wa.x + x1 * (double)wc.x;
        acc[1] += x0 * (double)wa.y + x1 * (double)wc.y;
        acc[2] += x0 * (double)wa.z + x1 * (double)wc.z;
        acc[3] += x0 * (double)wa.w + x1 * (double)wc.w;
        acc[4] += x0 * (double)wb.x + x1 * (double)wd.x;
        acc[5] += x0 * (double)wb.y + x1 * (double)wd.y;
        acc[6] += x0 * (double)wb.z + x1 * (double)wd.z;
        acc[7] += x0 * (double)wb.w + x1 * (double)wd.w;
    }
#pragma unroll
    for (int s = 32; s > 0; s >>= 1) {
#pragma unroll
        for (int e = 0; e < E_NUM; ++e) acc[e] += __shfl_xor(acc[e], s);
    }
    double mx = acc[0];
#pragma unroll
    for (int e = 1; e < E_NUM; ++e) mx = fmax(mx, acc[e]);
    double p[E_NUM]; double sum = 0.0;
#pragma unroll
    for (int e = 0; e < E_NUM; ++e) { p[e] = exp(acc[e] - mx); sum += p[e]; }
    int i0 = 0;
#pragma unroll
    for (int e = 1; e < E_NUM; ++e) if (p[e] > p[i0]) i0 = e;
    int i1 = (i0 == 0) ? 1 : 0;
#pragma unroll
    for (int e = 0; e < E_NUM; ++e) if (e != i0 && p[e] > p[i1]) i1 = e;
    if (lane == 0) {
        epick[gwave] = i0 | (i1 << 8);
        ewgt[2 * gwave]     = (float)(p[i0] / sum);
        ewgt[2 * gwave + 1] = (float)(p[i1] / sum);
    }
}

// ---------------- bucket: block-aggregated scatter; 8 global atomics per block ----------------
__global__ __launch_bounds__(256) void bucket_kernel(
    const int* __restrict__ epick, int* __restrict__ cnt,
    int* __restrict__ tok, int* __restrict__ eidx, int T) {
    __shared__ int lcnt[E_NUM];
    __shared__ int gbase[E_NUM];
    int b = blockIdx.x, tid = threadIdx.x;
    if (tid < E_NUM) lcnt[tid] = 0;
    __syncthreads();
    int t = b * 128 + (tid >> 1);
    int j = tid & 1;
    int e = (epick[t] >> (j * 8)) & 0xff;
    int li = atomicAdd(&lcnt[e], 1);
    __syncthreads();
    if (tid < E_NUM) gbase[tid] = atomicAdd(&cnt[tid], lcnt[tid]);
    __syncthreads();
    int slot = gbase[e] + li;
    tok[e * T + slot] = t;
    eidx[2 * t + j] = (e << 16) | slot;
}

// ---------------- prefix + compacted work table ----------------
// wtab[j] = (e<<16)|mblk for every live 128-row m-tile, in (e, mblk) order;
// -1 sentinels up to wmax. sum(ceil(M_e/128)) <= 2T/128 + E = wmax, so no
// overflow. Removes the ~75% dead-dispatch blocks from both GEMM grids
// (r5 counters: gemm occupancy ~2.4-3.2 blocks/CU despite resource bound of
// ~8 — dispatch-side, not resource-side).
__global__ void prefix_kernel(const int* __restrict__ cnt, int* __restrict__ base,
                              int* __restrict__ wtab, int wmax) {
    if (threadIdx.x == 0) {
        int a = 0;
#pragma unroll
        for (int e = 0; e < E_NUM; ++e) { base[e] = a; a += cnt[e]; }
        int nw = 0;
        for (int e = 0; e < E_NUM; ++e) {
            int nb = (cnt[e] + 127) >> 7;
            for (int mb = 0; mb < nb; ++mb) wtab[nw++] = (e << 16) | mb;
        }
        for (; nw < wmax; ++nw) wtab[nw] = -1;
    }
}

// ---------------- unified W1/W2 transpose, 64x64 tiles, packed stores ----------------
// W1: [E][D][H] f32 -> w1t [E][H][D] bf16 (no perm).
// W2: [E][H][D] f32 -> w2t [E][D][H] bf16 with K(=H) perm pi(j)=(j&3)*16+(j>>2) per 64-block.
__global__ __launch_bounds__(256) void transpose_both_kernel(
    const float* __restrict__ W1, const float* __restrict__ W2,
    __hip_bfloat16* __restrict__ w1t, __hip_bfloat16* __restrict__ w2t) {
    __shared__ float tile[64][65];
    int e = blockIdx.z;
    int id = blockIdx.x;
    const float* src; unsigned short* dst; int R, C, r0, c0, perm;
    if (id < 1024) {  // W1: R=D rows, C=H cols
        R = D_DIM; C = H_DIM;
        r0 = (id >> 6) * 64; c0 = (id & 63) * 64;
        src = W1 + (size_t)e * D_DIM * H_DIM;
        dst = (unsigned short*)(w1t + (size_t)e * H_DIM * D_DIM);
        perm = 0;
    } else {          // W2: R=H rows, C=D cols
        id -= 1024;
        R = H_DIM; C = D_DIM;
        r0 = (id >> 4) * 64; c0 = (id & 15) * 64;
        src = W2 + (size_t)e * H_DIM * D_DIM;
        dst = (unsigned short*)(w2t + (size_t)e * D_DIM * H_DIM);
        perm = 1;
    }
    int tx = threadIdx.x, ty = threadIdx.y;  // 32 x 8
#pragma unroll
    for (int i = 0; i < 8; ++i) {
        int j = ty + i * 8;
        int sr = perm ? ((j & 3) * 16 + (j >> 2)) : j;
        float2 v = *(const float2*)(src + (size_t)(r0 + sr) * C + c0 + 2 * tx);
        tile[j][2 * tx] = v.x; tile[j][2 * tx + 1] = v.y;
    }
    __syncthreads();
#pragma unroll
    for (int i = 0; i < 8; ++i) {
        int cc = ty + i * 8;
        unsigned pk = (unsigned)f2b(tile[2 * tx][cc]) | ((unsigned)f2b(tile[2 * tx + 1][cc]) << 16);
        *(unsigned*)(dst + (size_t)(c0 + cc) * R + r0 + 2 * tx) = pk;
    }
}

// ====================== GEMMs: proven 128x128 2-barrier structure, compacted grid ======================
// Optimization ledger (harness-measured):
//  - 256x256 counted-vmcnt coarse (r2): 282us, MfmaUtil 22 — REGRESSED (m196 pattern)
//  - 256x256 fine-phase m201-port (r3): 242us, MfmaUtil 25.6 — REGRESSED
//  - T1 XCD chunked swizzle (r4): FETCH 173->250MB — REGRESSED (early-exit grid)
//  - gemm2 split-K removal (r5): 243us, FETCH 620MB, occ 24% — REGRESSED
//    (split-K=2's value is BLOCK SUPPLY for latency hiding, not amortization)
//  -> 128x128 / BK=32 / 4-wave / 2-barrier at ~3 blocks/CU is the measured
//     optimum; r6 adds grid compaction via wtab (dead dispatches removed).
// LDS K-chunk swizzle (BK=32, 64 B rows = 4 chunks): row r chunk k stored at
// chunk r*4 + (k ^ ((r>>1)&3)). Writer (async, dest = base+lane*16): lane
// sources global chunk (lane&3)^((lane>>3)&3) of row (lane>>2). Reader: chunk
// q of row ra at byte ra*64 + ((q ^ ((ra>>1)&3))<<4). Conflict-free (measured
// SQ_LDS_BANK_CONFLICT = 0). Keep BK=32 (BK=64 regressed: occupancy 41->21).

// ---------------- GEMM1: h[slot, perm(col)] = gelu(x[tok] @ W1[e] + b1[e]), BK=32 ----------------
__global__ __launch_bounds__(256) void gemm1_kernel(
    const __hip_bfloat16* __restrict__ xb,   // [T][D]
    const __hip_bfloat16* __restrict__ w1t,  // [E][H][D] (B^T)
    const float* __restrict__ b1,            // [E][H]
    const int* __restrict__ cnt, const int* __restrict__ base,
    const int* __restrict__ tok, const int* __restrict__ wtab,
    __hip_bfloat16* __restrict__ hbuf,       // [2T][H] (N-permuted)
    int T) {
    int wt = wtab[blockIdx.y];
    if (wt < 0) return;
    int e = wt >> 16;
    int m0 = (wt & 0xffff) << 7;
    int M = cnt[e];
    int n0 = blockIdx.x * 128;
    const __hip_bfloat16* Bp = w1t + (size_t)e * H_DIM * D_DIM;

    __shared__ __align__(16) short sA[128 * 32];
    __shared__ __align__(16) short sB[128 * 32];
    __shared__ float sBias[128];
    char* sAc = (char*)sA; char* sBc = (char*)sB;

    int tid = threadIdx.x;
    int w = tid >> 6, lane = tid & 63;
    int wm = w >> 1, wn = w & 1;
    int q = lane >> 4, l4 = lane & 15;

    if (tid < 128) sBias[tid] = b1[e * H_DIM + n0 + tid];

    int kswz = ((lane & 3) ^ ((lane >> 3) & 3)) << 3;  // swizzled element offset
    int r0 = w * 32 + (lane >> 2);
    int r1 = r0 + 16;
    int tA0 = tok[e * T + min(m0 + r0, M - 1)];
    int tA1 = tok[e * T + min(m0 + r1, M - 1)];
    const __hip_bfloat16* gA0 = xb + (size_t)tA0 * D_DIM + kswz;
    const __hip_bfloat16* gA1 = xb + (size_t)tA1 * D_DIM + kswz;
    const __hip_bfloat16* gB0 = Bp + (size_t)(n0 + r0) * D_DIM + kswz;
    const __hip_bfloat16* gB1 = Bp + (size_t)(n0 + r1) * D_DIM + kswz;
    char* lA0 = sAc + w * 2048 + lane * 16;
    char* lB0 = sBc + w * 2048 + lane * 16;
    char* lA1 = sAc + w * 2048 + 1024;  // wave's second segment base
    char* lB1 = sBc + w * 2048 + 1024;

    f32x4 acc[4][4];
#pragma unroll
    for (int a = 0; a < 4; ++a)
#pragma unroll
        for (int b = 0; b < 4; ++b) acc[a][b] = (f32x4){0.f, 0.f, 0.f, 0.f};

    for (int kk = 0; kk < D_DIM; kk += 32) {
        async_load16(gA0 + kk, lA0);
        async_load16(gA1 + kk, lA1);
        async_load16(gB0 + kk, lB0);
        async_load16(gB1 + kk, lB1);
        __syncthreads();
        short8 aF[4], bF[4];
#pragma unroll
        for (int t = 0; t < 4; ++t) {
            int ra = wm * 64 + t * 16 + l4;
            aF[t] = *(const short8*)(sAc + ra * 64 + ((q ^ ((ra >> 1) & 3)) << 4));
            int rb = wn * 64 + t * 16 + l4;
            bF[t] = *(const short8*)(sBc + rb * 64 + ((q ^ ((rb >> 1) & 3)) << 4));
        }
#pragma unroll
        for (int tm = 0; tm < 4; ++tm)
#pragma unroll
            for (int tn = 0; tn < 4; ++tn)
                acc[tm][tn] = __builtin_amdgcn_mfma_f32_16x16x32_bf16(aF[tm], bF[tn], acc[tm][tn], 0, 0, 0);
        __syncthreads();
    }

    int sb = base[e];
    unsigned short* hs = (unsigned short*)hbuf;
#pragma unroll
    for (int tm = 0; tm < 4; ++tm) {
        int rbase = wm * 64 + tm * 16 + q * 4;
#pragma unroll
        for (int i = 0; i < 4; ++i) {
            int row = m0 + rbase + i;
            if (row < M) {
                size_t hrow = (size_t)(sb + row) * H_DIM;
                ushort4v pk;
#pragma unroll
                for (int tn = 0; tn < 4; ++tn) {
                    float v = acc[tm][tn][i] + sBias[wn * 64 + tn * 16 + l4];
                    pk[tn] = f2b(gelu_fast(v));
                }
                *(ushort4v*)(hs + hrow + n0 + wn * 64 + l4 * 4) = pk;
            }
        }
    }
}

// ---------------- GEMM2 (split-K=2, BK=32): ybuf[kc][slot, perm(col)] = partial(h @ W2[e]) ----------------
__global__ __launch_bounds__(256) void gemm2_kernel(
    const __hip_bfloat16* __restrict__ hbuf, // [2T][H] (K-permuted, matches w2t)
    const __hip_bfloat16* __restrict__ w2t,  // [E][D][H] (B^T, K-permuted)
    const int* __restrict__ cnt, const int* __restrict__ base,
    const int* __restrict__ wtab,
    __hip_bfloat16* __restrict__ ybuf,       // [2][2T][D] (N-permuted)
    int T) {
    int wt = wtab[blockIdx.y];
    if (wt < 0) return;
    int e = wt >> 16;
    int m0 = (wt & 0xffff) << 7;
    int kc = blockIdx.z;
    int M = cnt[e];
    int n0 = blockIdx.x * 128;
    int sb = base[e];
    const __hip_bfloat16* Bp = w2t + (size_t)e * D_DIM * H_DIM;

    __shared__ __align__(16) short sA[128 * 32];
    __shared__ __align__(16) short sB[128 * 32];
    char* sAc = (char*)sA; char* sBc = (char*)sB;

    int tid = threadIdx.x;
    int w = tid >> 6, lane = tid & 63;
    int wm = w >> 1, wn = w & 1;
    int q = lane >> 4, l4 = lane & 15;

    int kswz = ((lane & 3) ^ ((lane >> 3) & 3)) << 3;
    int r0 = w * 32 + (lane >> 2);
    int r1 = r0 + 16;
    const __hip_bfloat16* gA0 = hbuf + (size_t)(sb + min(m0 + r0, M - 1)) * H_DIM + kswz;
    const __hip_bfloat16* gA1 = hbuf + (size_t)(sb + min(m0 + r1, M - 1)) * H_DIM + kswz;
    const __hip_bfloat16* gB0 = Bp + (size_t)(n0 + r0) * H_DIM + kswz;
    const __hip_bfloat16* gB1 = Bp + (size_t)(n0 + r1) * H_DIM + kswz;
    char* lA0 = sAc + w * 2048 + lane * 16;
    char* lB0 = sBc + w * 2048 + lane * 16;
    char* lA1 = sAc + w * 2048 + 1024;
    char* lB1 = sBc + w * 2048 + 1024;

    f32x4 acc[4][4];
#pragma unroll
    for (int a = 0; a < 4; ++a)
#pragma unroll
        for (int b = 0; b < 4; ++b) acc[a][b] = (f32x4){0.f, 0.f, 0.f, 0.f};

    int k0 = kc * (H_DIM / 2), k1 = k0 + (H_DIM / 2);
    for (int kk = k0; kk < k1; kk += 32) {
        async_load16(gA0 + kk, lA0);
        async_load16(gA1 + kk, lA1);
        async_load16(gB0 + kk, lB0);
        async_load16(gB1 + kk, lB1);
        __syncthreads();
        short8 aF[4], bF[4];
#pragma unroll
        for (int t = 0; t < 4; ++t) {
            int ra = wm * 64 + t * 16 + l4;
            aF[t] = *(const short8*)(sAc + ra * 64 + ((q ^ ((ra >> 1) & 3)) << 4));
            int rb = wn * 64 + t * 16 + l4;
            bF[t] = *(const short8*)(sBc + rb * 64 + ((q ^ ((rb >> 1) & 3)) << 4));
        }
#pragma unroll
        for (int tm = 0; tm < 4; ++tm)
#pragma unroll
            for (int tn = 0; tn < 4; ++tn)
                acc[tm][tn] = __builtin_amdgcn_mfma_f32_16x16x32_bf16(aF[tm], bF[tn], acc[tm][tn], 0, 0, 0);
        __syncthreads();
    }

    size_t ybase = (size_t)kc * 2 * T;
    unsigned short* ys = (unsigned short*)ybuf;
#pragma unroll
    for (int tm = 0; tm < 4; ++tm) {
        int rbase = wm * 64 + tm * 16 + q * 4;
#pragma unroll
        for (int i = 0; i < 4; ++i) {
            int row = m0 + rbase + i;
            if (row < M) {
                size_t yrow = (ybase + sb + row) * D_DIM;
                ushort4v pk;
#pragma unroll
                for (int tn = 0; tn < 4; ++tn) pk[tn] = f2b(acc[tm][tn][i]);
                *(ushort4v*)(ys + yrow + n0 + wn * 64 + l4 * 4) = pk;
            }
        }
    }
}

// ---------------- combine: out[t, pi(c)] = sum_j w_j * (y_j(p0)+y_j(p1) + b2[e_j]) ----------------
__global__ __launch_bounds__(256) void combine_kernel(
    const __hip_bfloat16* __restrict__ yb, const float* __restrict__ b2,
    const int* __restrict__ base, const int* __restrict__ eidx,
    const float* __restrict__ ewgt, float* __restrict__ out, int T) {
    int t = blockIdx.x, tid = threadIdx.x;
    int v0 = eidx[2 * t], v1 = eidx[2 * t + 1];
    float w0 = ewgt[2 * t], w1 = ewgt[2 * t + 1];
    int e0 = v0 >> 16, e1 = v1 >> 16;
    size_t g0 = (size_t)base[e0] + (v0 & 0xffff);
    size_t g1 = (size_t)base[e1] + (v1 & 0xffff);
    int c = tid * 4;               // stored (permuted) col
    int blk = c >> 6;
    int tt = (c >> 2) & 15;
    size_t off2 = (size_t)2 * T * D_DIM;
    const short* ys = (const short*)yb;
    short4v a0 = *(const short4v*)(ys + g0 * D_DIM + c);
    short4v a1 = *(const short4v*)(ys + off2 + g0 * D_DIM + c);
    short4v c0 = *(const short4v*)(ys + g1 * D_DIM + c);
    short4v c1 = *(const short4v*)(ys + off2 + g1 * D_DIM + c);
    float s0[4] = { b2f(a0.x) + b2f(a1.x), b2f(a0.y) + b2f(a1.y),
                    b2f(a0.z) + b2f(a1.z), b2f(a0.w) + b2f(a1.w) };
    float s1[4] = { b2f(c0.x) + b2f(c1.x), b2f(c0.y) + b2f(c1.y),
                    b2f(c0.z) + b2f(c1.z), b2f(c0.w) + b2f(c1.w) };
    float* orow = out + (size_t)t * D_DIM;
#pragma unroll
    for (int s = 0; s < 4; ++s) {
        int oc = blk * 64 + s * 16 + tt;   // original col
        float o = w0 * (s0[s] + b2[(size_t)e0 * D_DIM + oc]) +
                  w1 * (s1[s] + b2[(size_t)e1 * D_DIM + oc]);
        orow[oc] = o;
    }
}

extern "C" void kernel_launch(void* const* d_in, const int* in_sizes, int n_in,
                              void* d_out, int out_size, void* d_ws, size_t ws_size,
                              hipStream_t stream) {
    const float* x  = (const float*)d_in[0];
    const float* Wg = (const float*)d_in[1];
    const float* W1 = (const float*)d_in[2];
    const float* b1 = (const float*)d_in[3];
    const float* W2 = (const float*)d_in[4];
    const float* b2 = (const float*)d_in[5];
    int T = in_sizes[0] / D_DIM;  // 8192
    int wmax = 2 * T / 128 + E_NUM;  // 136: upper bound on live m-tiles

    char* p = (char*)d_ws;
    int* cnt   = (int*)p;
    int* base  = (int*)(p + 256);
    int* tok   = (int*)(p + 512);
    int* eidx  = (int*)(p + 512 + 4ll * E_NUM * T);
    float* ewgt = (float*)(p + 512 + 4ll * E_NUM * T + 8ll * T);
    int* epick = (int*)(p + 512 + 4ll * E_NUM * T + 16ll * T);
    int* wtab  = (int*)(p + 512 + 4ll * E_NUM * T + 20ll * T);
    char* pb = p + 512 + 4ll * E_NUM * T + 20ll * T + 1024;
    __hip_bfloat16* xb  = (__hip_bfloat16*)pb;
    __hip_bfloat16* w1t = xb + (size_t)T * D_DIM;
    __hip_bfloat16* w2t = w1t + (size_t)E_NUM * H_DIM * D_DIM;
    __hip_bfloat16* hb  = w2t + (size_t)E_NUM * H_DIM * D_DIM;
    // ybuf [2][2T][D] bf16 (67 MB) aliases xb+w1t (dead by gemm2 time).
    __hip_bfloat16* yb  = xb;

    hipMemsetAsync(cnt, 0, 256, stream);

    router_kernel<<<dim3((T + 3) / 4), 256, 0, stream>>>(x, Wg, xb, epick, ewgt, T);
    bucket_kernel<<<dim3(T / 128), 256, 0, stream>>>(epick, cnt, tok, eidx, T);
    prefix_kernel<<<1, 64, 0, stream>>>(cnt, base, wtab, wmax);
    transpose_both_kernel<<<dim3(2048, 1, E_NUM), dim3(32, 8), 0, stream>>>(W1, W2, w1t, w2t);
    gemm1_kernel<<<dim3(H_DIM / 128, wmax, 1), 256, 0, stream>>>(xb, w1t, b1, cnt, base, tok, wtab, hb, T);
    gemm2_kernel<<<dim3(D_DIM / 128, wmax, 2), 256, 0, stream>>>(hb, w2t, cnt, base, wtab, yb, T);
    combine_kernel<<<T, 256, 0, stream>>>(yb, b2, base, eidx, ewgt, (float*)d_out, T);
}